// Round 2
// baseline (270.868 us; speedup 1.0000x reference)
//
#include <hip/hip_runtime.h>
#include <math.h>

// Problem constants (fixed by the reference)
constexpr int kEmb    = 128;
constexpr int kRegion = 7;
constexpr int kRadius = 3;
constexpr int kBatch  = 32;
constexpr int kSeq    = 1024;
constexpr int kPos    = kBatch * kSeq;
constexpr int kHalf   = kPos / 2;        // 16384

typedef float f32x4 __attribute__((ext_vector_type(4)));  // native vec for NT store

// h[b,s,e] = max_r U_full[win*7+r][e] * W_full[t][e]
//   W_full[t]     = (t > 0) ? W[t-1]         : 0
//   U_full[t*7+r] = (t > 0) ? U[(t-1)*7 + r] : 0   (covers padding AND token 0)
//
// R6 = revert of R5's shfl token broadcast (it serialized the critical path:
// guarded load -> vmcnt -> 14x ds_bpermute -> lgkmcnt -> U-address, +45% on the
// kernel residual). Restore R4's per-lane broadcast token loads (L1-cheap,
// lets gathers pipeline against token arrivals). KEEP R5's 32-bit byte-offset
// addressing (saddr-form loads, no v_lshl_add_u64 chains) — independent of the
// regression mechanism.
// Structure: two positions per 32-lane group (p, p+kPos/2), all 14 token loads
// up front, then 2 W + 14 U gathers issued back-to-back, NT stores.
__global__ __launch_bounds__(256) void region_encoder_kernel(
    const int*   __restrict__ seq,   // (32, 1024)
    const float* __restrict__ W,     // (49999, 128)
    const float* __restrict__ U,     // (349993, 128)
    float*       __restrict__ out)   // (32, 1024, 128)
{
    const int lane = threadIdx.x & 31;
    const int grp  = threadIdx.x >> 5;           // 0..7
    const int p0   = blockIdx.x * 8 + grp;       // 0 .. kHalf-1
    const int p1   = p0 + kHalf;
    const int b0   = p0 >> 10, s0 = p0 & (kSeq - 1);
    const int b1   = p1 >> 10, s1 = p1 & (kSeq - 1);
    const unsigned laneB = (unsigned)lane * 16u; // byte offset of this lane's float4

    // ---- all token loads for BOTH positions, issued together (broadcast loads) ----
    int tok0[kRegion], tok1[kRegion];
#pragma unroll
    for (int r = 0; r < kRegion; ++r) {
        const int sp0 = s0 + r - kRadius;
        tok0[r] = ((unsigned)sp0 < (unsigned)kSeq)
                    ? *(const int*)((const char*)seq + (unsigned)(b0 * kSeq + sp0) * 4u)
                    : 0;
        const int sp1 = s1 + r - kRadius;
        tok1[r] = ((unsigned)sp1 < (unsigned)kSeq)
                    ? *(const int*)((const char*)seq + (unsigned)(b1 * kSeq + sp1) * 4u)
                    : 0;
    }

    // ---- W rows for both center tokens (32-bit byte offsets) ----
    const int t0 = tok0[kRadius];
    const int t1 = tok1[kRadius];
    f32x4 wv0 = {0.f, 0.f, 0.f, 0.f};
    f32x4 wv1 = {0.f, 0.f, 0.f, 0.f};
    if (t0 > 0)
        wv0 = *(const f32x4*)((const char*)W + ((unsigned)(t0 - 1) * 512u + laneB));
    if (t1 > 0)
        wv1 = *(const f32x4*)((const char*)W + ((unsigned)(t1 - 1) * 512u + laneB));

    // ---- all 14 U-row gathers, issued back-to-back ----
    f32x4 uv0[kRegion], uv1[kRegion];
#pragma unroll
    for (int r = 0; r < kRegion; ++r) {
        uv0[r] = (f32x4){0.f, 0.f, 0.f, 0.f};
        if (tok0[r] > 0) {
            const unsigned off = ((unsigned)(tok0[r] - 1) * 7u + (unsigned)r) * 512u + laneB;
            uv0[r] = *(const f32x4*)((const char*)U + off);
        }
    }
#pragma unroll
    for (int r = 0; r < kRegion; ++r) {
        uv1[r] = (f32x4){0.f, 0.f, 0.f, 0.f};
        if (tok1[r] > 0) {
            const unsigned off = ((unsigned)(tok1[r] - 1) * 7u + (unsigned)r) * 512u + laneB;
            uv1[r] = *(const f32x4*)((const char*)U + off);
        }
    }

    // ---- consume position 0 ----
    f32x4 m0 = uv0[0] * wv0;
#pragma unroll
    for (int r = 1; r < kRegion; ++r) {
        const f32x4 p = uv0[r] * wv0;
        m0.x = fmaxf(m0.x, p.x);
        m0.y = fmaxf(m0.y, p.y);
        m0.z = fmaxf(m0.z, p.z);
        m0.w = fmaxf(m0.w, p.w);
    }
    __builtin_nontemporal_store(
        m0, (f32x4*)((char*)out + ((unsigned)p0 * 512u + laneB)));

    // ---- consume position 1 ----
    f32x4 m1 = uv1[0] * wv1;
#pragma unroll
    for (int r = 1; r < kRegion; ++r) {
        const f32x4 p = uv1[r] * wv1;
        m1.x = fmaxf(m1.x, p.x);
        m1.y = fmaxf(m1.y, p.y);
        m1.z = fmaxf(m1.z, p.z);
        m1.w = fmaxf(m1.w, p.w);
    }
    __builtin_nontemporal_store(
        m1, (f32x4*)((char*)out + ((unsigned)p1 * 512u + laneB)));
}

extern "C" void kernel_launch(void* const* d_in, const int* in_sizes, int n_in,
                              void* d_out, int out_size, void* d_ws, size_t ws_size,
                              hipStream_t stream) {
    const int*   seq = (const int*)d_in[0];
    const float* W   = (const float*)d_in[1];
    const float* U   = (const float*)d_in[2];
    float*       out = (float*)d_out;

    const int blocks = kHalf / 8;                // 2048 blocks, 16 positions each
    region_encoder_kernel<<<dim3(blocks), dim3(256), 0, stream>>>(seq, W, U, out);
}

// Round 3
// 252.117 us; speedup vs baseline: 1.0744x; 1.0744x over previous
//
#include <hip/hip_runtime.h>
#include <math.h>

// Problem constants (fixed by the reference)
constexpr int kEmb    = 128;
constexpr int kRegion = 7;
constexpr int kRadius = 3;
constexpr int kBatch  = 32;
constexpr int kSeq    = 1024;
constexpr int kPos    = kBatch * kSeq;
constexpr int kHalf   = kPos / 2;        // 16384

typedef float f32x4 __attribute__((ext_vector_type(4)));  // native vec for NT store

// h[b,s,e] = max_r U_full[win*7+r][e] * W_full[t][e]
//   W_full[t]     = (t > 0) ? W[t-1]         : 0
//   U_full[t*7+r] = (t > 0) ? U[(t-1)*7 + r] : 0   (covers padding AND token 0)
//
// R7: byte-identical revert to the measured-249.5us R4 kernel. This is a pure
// A/B discriminator: R5/R6 both carried 32-bit saddr-form addressing (the only
// shared diff vs R4) and both sat ~268-271us. If this run returns ~250, the
// 32-bit addressing was the regression (keep 64-bit size_t addressing: more
// addr VGPRs -> lower occupancy -> less gather thrash, or better compiler
// clustering). If it stays ~270, the environment drifted after R0 and the
// baseline must be re-anchored.
__global__ __launch_bounds__(256) void region_encoder_kernel(
    const int*   __restrict__ seq,   // (32, 1024)
    const float* __restrict__ W,     // (49999, 128)
    const float* __restrict__ U,     // (349993, 128)
    float*       __restrict__ out)   // (32, 1024, 128)
{
    const int lane = threadIdx.x & 31;
    const int grp  = threadIdx.x >> 5;           // 0..7
    const int p0   = blockIdx.x * 8 + grp;       // 0 .. kHalf-1
    const int p1   = p0 + kHalf;
    const int b0   = p0 >> 10, s0 = p0 & (kSeq - 1);
    const int b1   = p1 >> 10, s1 = p1 & (kSeq - 1);

    // ---- all token loads for BOTH positions, issued together ----
    int tok0[kRegion], tok1[kRegion];
#pragma unroll
    for (int r = 0; r < kRegion; ++r) {
        const int sp0 = s0 + r - kRadius;
        tok0[r] = (sp0 >= 0 && sp0 < kSeq) ? seq[b0 * kSeq + sp0] : 0;
        const int sp1 = s1 + r - kRadius;
        tok1[r] = (sp1 >= 0 && sp1 < kSeq) ? seq[b1 * kSeq + sp1] : 0;
    }

    // ---- W rows for both center tokens ----
    const int t0 = tok0[kRadius];
    const int t1 = tok1[kRadius];
    float4 wv0 = make_float4(0.f, 0.f, 0.f, 0.f);
    float4 wv1 = make_float4(0.f, 0.f, 0.f, 0.f);
    if (t0 > 0) wv0 = ((const float4*)(W + (size_t)(t0 - 1) * kEmb))[lane];
    if (t1 > 0) wv1 = ((const float4*)(W + (size_t)(t1 - 1) * kEmb))[lane];

    // ---- all 14 U-row loads, issued together ----
    float4 uv0[kRegion], uv1[kRegion];
#pragma unroll
    for (int r = 0; r < kRegion; ++r) {
        uv0[r] = make_float4(0.f, 0.f, 0.f, 0.f);
        if (tok0[r] > 0) {
            const size_t row = (size_t)(tok0[r] - 1) * kRegion + r;
            uv0[r] = ((const float4*)(U + row * kEmb))[lane];
        }
    }
#pragma unroll
    for (int r = 0; r < kRegion; ++r) {
        uv1[r] = make_float4(0.f, 0.f, 0.f, 0.f);
        if (tok1[r] > 0) {
            const size_t row = (size_t)(tok1[r] - 1) * kRegion + r;
            uv1[r] = ((const float4*)(U + row * kEmb))[lane];
        }
    }

    // ---- consume position 0 ----
    float4 m0;
    m0.x = uv0[0].x * wv0.x;
    m0.y = uv0[0].y * wv0.y;
    m0.z = uv0[0].z * wv0.z;
    m0.w = uv0[0].w * wv0.w;
#pragma unroll
    for (int r = 1; r < kRegion; ++r) {
        m0.x = fmaxf(m0.x, uv0[r].x * wv0.x);
        m0.y = fmaxf(m0.y, uv0[r].y * wv0.y);
        m0.z = fmaxf(m0.z, uv0[r].z * wv0.z);
        m0.w = fmaxf(m0.w, uv0[r].w * wv0.w);
    }
    {
        f32x4 v = { m0.x, m0.y, m0.z, m0.w };
        __builtin_nontemporal_store(v, &((f32x4*)out)[(size_t)p0 * (kEmb / 4) + lane]);
    }

    // ---- consume position 1 ----
    float4 m1;
    m1.x = uv1[0].x * wv1.x;
    m1.y = uv1[0].y * wv1.y;
    m1.z = uv1[0].z * wv1.z;
    m1.w = uv1[0].w * wv1.w;
#pragma unroll
    for (int r = 1; r < kRegion; ++r) {
        m1.x = fmaxf(m1.x, uv1[r].x * wv1.x);
        m1.y = fmaxf(m1.y, uv1[r].y * wv1.y);
        m1.z = fmaxf(m1.z, uv1[r].z * wv1.z);
        m1.w = fmaxf(m1.w, uv1[r].w * wv1.w);
    }
    {
        f32x4 v = { m1.x, m1.y, m1.z, m1.w };
        __builtin_nontemporal_store(v, &((f32x4*)out)[(size_t)p1 * (kEmb / 4) + lane]);
    }
}

extern "C" void kernel_launch(void* const* d_in, const int* in_sizes, int n_in,
                              void* d_out, int out_size, void* d_ws, size_t ws_size,
                              hipStream_t stream) {
    const int*   seq = (const int*)d_in[0];
    const float* W   = (const float*)d_in[1];
    const float* U   = (const float*)d_in[2];
    float*       out = (float*)d_out;

    const int blocks = kHalf / 8;                // 2048 blocks, 16 positions each
    region_encoder_kernel<<<dim3(blocks), dim3(256), 0, stream>>>(seq, W, U, out);
}